// Round 17
// baseline (115.960 us; speedup 1.0000x reference)
//
#include <hip/hip_runtime.h>
#include <hip/hip_bf16.h>

typedef __attribute__((ext_vector_type(8))) short bfx8;
typedef __attribute__((ext_vector_type(4))) short bfx4;
typedef __attribute__((ext_vector_type(4))) float f32x4;
typedef __attribute__((ext_vector_type(4))) unsigned int u32x4;
typedef __attribute__((ext_vector_type(2))) unsigned int u32x2;

#define T_SEQ 4096
#define C_DIM 768
#define NH    12
#define HD    64
#define QKV_N 2304
#define QK_N  1536

#define MFMA16(a, b, c) __builtin_amdgcn_mfma_f32_16x16x32_bf16((a), (b), (c), 0, 0, 0)

#if __has_builtin(__builtin_amdgcn_exp2f)
#define EXP2(x) __builtin_amdgcn_exp2f(x)
#else
#define EXP2(x) exp2f(x)
#endif

__device__ __forceinline__ short f2bf(float f) {
  __hip_bfloat16 h = __float2bfloat16(f);
  return __builtin_bit_cast(short, h);
}

// pack two f32 -> u32 of 2 bf16 (truncation): (hi16(odd)<<16)|hi16(even), 1 op
__device__ __forceinline__ unsigned packtrunc(float p_even, float p_odd) {
#if __has_builtin(__builtin_amdgcn_perm)
  return __builtin_amdgcn_perm(__builtin_bit_cast(unsigned, p_odd),
                               __builtin_bit_cast(unsigned, p_even), 0x07060302u);
#else
  return (__builtin_bit_cast(unsigned, p_odd) & 0xFFFF0000u) |
         (__builtin_bit_cast(unsigned, p_even) >> 16);
#endif
}

// permlane swaps via builtins (hazard-safe); used ONLY for P-redistribution.
__device__ __forceinline__ void pl16(unsigned& a, unsigned& b) {
#if __has_builtin(__builtin_amdgcn_permlane16_swap)
  u32x2 r = __builtin_amdgcn_permlane16_swap(a, b, false, false);
  a = r[0]; b = r[1];
#else
  unsigned ax = (unsigned)__shfl_xor((int)a, 16, 64);
  unsigned bx = (unsigned)__shfl_xor((int)b, 16, 64);
  bool odd = ((threadIdx.x >> 4) & 1) != 0;
  unsigned na = odd ? bx : a;
  unsigned nb = odd ? b : ax;
  a = na; b = nb;
#endif
}
__device__ __forceinline__ void pl32(unsigned& a, unsigned& b) {
#if __has_builtin(__builtin_amdgcn_permlane32_swap)
  u32x2 r = __builtin_amdgcn_permlane32_swap(a, b, false, false);
  a = r[0]; b = r[1];
#else
  unsigned ax = (unsigned)__shfl_xor((int)a, 32, 64);
  unsigned bx = (unsigned)__shfl_xor((int)b, 32, 64);
  bool hi = ((threadIdx.x >> 5) & 1) != 0;
  unsigned na = hi ? bx : a;
  unsigned nb = hi ? b : ax;
  a = na; b = nb;
#endif
}

// ---------------- fused prep: x->bf16 | w_attn^T (Q-scaled) | w_proj^T ----------------
#define NB_CONV 3072
#define NB_TA   (72 * 24)
#define NB_TB   (24 * 24)
__global__ __launch_bounds__(256) void prep_kernel(
    const float* __restrict__ x, short* __restrict__ xb,
    const float* __restrict__ w_attn, short* __restrict__ wab,
    const float* __restrict__ w_proj, short* __restrict__ wpb) {
  __shared__ short tile[32][33];
  const int b = blockIdx.x;
  if (b < NB_CONV) {
    int i = b * 256 + threadIdx.x;
    float4 v = ((const float4*)x)[i];
    bfx4 o;
    o[0] = f2bf(v.x); o[1] = f2bf(v.y); o[2] = f2bf(v.z); o[3] = f2bf(v.w);
    ((bfx4*)xb)[i] = o;
    return;
  }
  const float* in; short* out; int Cc, bx, by, qcols;
  if (b < NB_CONV + NB_TA) {
    int bb = b - NB_CONV;
    in = w_attn; out = wab; Cc = QKV_N;
    bx = (bb % 72) * 32; by = (bb / 72) * 32;
    qcols = C_DIM;  // scale Q columns by 0.125*log2(e)
  } else {
    int bb = b - NB_CONV - NB_TA;
    in = w_proj; out = wpb; Cc = C_DIM;
    bx = (bb % 24) * 32; by = (bb / 24) * 32;
    qcols = 0;
  }
  int tx = threadIdx.x & 31, ty = threadIdx.x >> 5;  // 32x8
  float sc = (bx + tx) < qcols ? 0.125f * 1.4426950408889634f : 1.0f;
#pragma unroll
  for (int i = 0; i < 32; i += 8)
    tile[ty + i][tx] = f2bf(in[(size_t)(by + ty + i) * Cc + (bx + tx)] * sc);
  __syncthreads();
#pragma unroll
  for (int i = 0; i < 32; i += 8)
    out[(size_t)(bx + ty + i) * C_DIM + (by + tx)] = tile[tx][ty + i];
}

// ---------------- bf16 GEMM (128x96, BK=64): QKV with fused V-transpose ----------------
// Round-12 lockstep schedule, BK doubled to 64: nk=12 K-steps (was 24) ->
// half the barriers/vmcnt-waits, 24 MFMA/wave between syncs (was 12).
// LDS 64 KB -> 2 blocks/CU (8 waves/CU). STAGE = 8 loads, vmcnt(8).
__global__ __launch_bounds__(256) void gemm_qkv(
    const short* __restrict__ A, const short* __restrict__ Bt,
    short* __restrict__ qk, short* __restrict__ Vt, int K) {
  __shared__ short As[2][128 * 64];
  __shared__ short Bs[2][128 * 64];
  const int tid  = threadIdx.x;
  const int lane = tid & 63;
  const int wave = tid >> 6;
  const int am0 = blockIdx.x * 128;
  const int bn0 = blockIdx.y * 96;
  const int wr = (wave >> 1) * 64;
  const int wc = (wave & 1) * 48;

  // 4 x 16B slots per thread per tensor: idx in [0,1024), row = idx>>3, col8 = idx&7
  int srow[4], scol[4], sidx[4], sbrow[4];
#pragma unroll
  for (int i = 0; i < 4; i++) {
    sidx[i] = i * 256 + tid;
    srow[i] = sidx[i] >> 3;
    scol[i] = (sidx[i] & 7) * 8;
    sbrow[i] = (srow[i] < 96) ? srow[i] : 95;  // B row clamp (pad rows dup 95)
  }

#define GSTAGE(buf, k0)                                                                 \
  do {                                                                                  \
    _Pragma("unroll") for (int i = 0; i < 4; i++) {                                     \
      __builtin_amdgcn_global_load_lds(                                                 \
          (const __attribute__((address_space(1))) void*)(A + (size_t)(am0 + srow[i]) * K + (k0) + scol[i]), \
          (__attribute__((address_space(3))) void*)(&As[buf][sidx[i] * 8]), 16, 0, 0);  \
      __builtin_amdgcn_global_load_lds(                                                 \
          (const __attribute__((address_space(1))) void*)(Bt + (size_t)(bn0 + sbrow[i]) * K + (k0) + scol[i]), \
          (__attribute__((address_space(3))) void*)(&Bs[buf][sidx[i] * 8]), 16, 0, 0);  \
    }                                                                                   \
  } while (0)

  const f32x4 zero = {0.f, 0.f, 0.f, 0.f};
  f32x4 acc[4][3];
#pragma unroll
  for (int i = 0; i < 4; i++)
#pragma unroll
    for (int j = 0; j < 3; j++) acc[i][j] = zero;

  const int aoff = (wr + (lane & 15)) * 64 + (lane >> 4) * 8;
  const int boff = (wc + (lane & 15)) * 64 + (lane >> 4) * 8;

  const int nk = K / 64;  // 12
  GSTAGE(0, 0);
  for (int t = 0; t < nk; t++) {
    const int cur = t & 1;
    if (t + 1 < nk) {
      GSTAGE(cur ^ 1, (t + 1) * 64);
      asm volatile("s_waitcnt vmcnt(8)" ::: "memory");
    } else {
      asm volatile("s_waitcnt vmcnt(0)" ::: "memory");
    }
    __builtin_amdgcn_s_barrier();

#pragma unroll
    for (int kk = 0; kk < 2; kk++) {
      bfx8 a[4], b[3];
#pragma unroll
      for (int mf = 0; mf < 4; mf++)
        a[mf] = *(const bfx8*)&As[cur][aoff + kk * 32 + mf * 16 * 64];
#pragma unroll
      for (int nf = 0; nf < 3; nf++)
        b[nf] = *(const bfx8*)&Bs[cur][boff + kk * 32 + nf * 16 * 64];
#pragma unroll
      for (int mf = 0; mf < 4; mf++)
#pragma unroll
        for (int nf = 0; nf < 3; nf++)
          acc[mf][nf] = MFMA16(a[mf], b[nf], acc[mf][nf]);
    }

    asm volatile("s_waitcnt lgkmcnt(0)" ::: "memory");
    __builtin_amdgcn_s_barrier();
  }
#undef GSTAGE

  if (bn0 >= QK_N) {
#pragma unroll
    for (int mf = 0; mf < 4; mf++) {
      int row0 = am0 + wr + mf * 16 + (lane >> 4) * 4;
#pragma unroll
      for (int nf = 0; nf < 3; nf++) {
        int colV = bn0 - QK_N + wc + nf * 16 + (lane & 15);
        bfx4 ov;
#pragma unroll
        for (int r = 0; r < 4; r++) ov[r] = f2bf(acc[mf][nf][r]);
        *(bfx4*)&Vt[(size_t)colV * T_SEQ + row0] = ov;
      }
    }
  } else {
#pragma unroll
    for (int mf = 0; mf < 4; mf++) {
#pragma unroll
      for (int r = 0; r < 4; r++) {
        int row = am0 + wr + mf * 16 + (lane >> 4) * 4 + r;
#pragma unroll
        for (int nf = 0; nf < 3; nf++) {
          int col = bn0 + wc + nf * 16 + (lane & 15);
          qk[(size_t)row * QK_N + col] = f2bf(acc[mf][nf][r]);
        }
      }
    }
  }
}

// ---------------- bf16 GEMM (64x64, f32 out): projection (round-12 proven) ----------------
__global__ __launch_bounds__(256) void gemm_proj(
    const short* __restrict__ A, const short* __restrict__ Bt,
    float* __restrict__ C, int N, int K) {
  __shared__ short As[2][64 * 32];
  __shared__ short Bs[2][64 * 32];
  const int tid  = threadIdx.x;
  const int lane = tid & 63;
  const int wave = tid >> 6;
  const int am0 = blockIdx.x * 64;
  const int bn0 = blockIdx.y * 64;
  const int wr = (wave >> 1) * 32;
  const int wc = (wave & 1) * 32;

  const int r0 = tid >> 2, c0 = (tid & 3) * 8;

#define PSTAGE(buf, k0)                                                                 \
  do {                                                                                  \
    __builtin_amdgcn_global_load_lds(                                                   \
        (const __attribute__((address_space(1))) void*)(A + (size_t)(am0 + r0) * K + (k0) + c0), \
        (__attribute__((address_space(3))) void*)(&As[buf][tid * 8]), 16, 0, 0);        \
    __builtin_amdgcn_global_load_lds(                                                   \
        (const __attribute__((address_space(1))) void*)(Bt + (size_t)(bn0 + r0) * K + (k0) + c0), \
        (__attribute__((address_space(3))) void*)(&Bs[buf][tid * 8]), 16, 0, 0);        \
  } while (0)

  const f32x4 zero = {0.f, 0.f, 0.f, 0.f};
  f32x4 acc[2][2];
#pragma unroll
  for (int i = 0; i < 2; i++)
#pragma unroll
    for (int j = 0; j < 2; j++) acc[i][j] = zero;

  const int aoff = (wr + (lane & 15)) * 32 + (lane >> 4) * 8;
  const int boff = (wc + (lane & 15)) * 32 + (lane >> 4) * 8;

  const int nk = K / 32;
  PSTAGE(0, 0);
  for (int t = 0; t < nk; t++) {
    const int cur = t & 1;
    if (t + 1 < nk) {
      PSTAGE(cur ^ 1, (t + 1) * 32);
      asm volatile("s_waitcnt vmcnt(2)" ::: "memory");
    } else {
      asm volatile("s_waitcnt vmcnt(0)" ::: "memory");
    }
    __builtin_amdgcn_s_barrier();

    bfx8 a[2], b[2];
#pragma unroll
    for (int mf = 0; mf < 2; mf++)
      a[mf] = *(const bfx8*)&As[cur][aoff + mf * 16 * 32];
#pragma unroll
    for (int nf = 0; nf < 2; nf++)
      b[nf] = *(const bfx8*)&Bs[cur][boff + nf * 16 * 32];
#pragma unroll
    for (int mf = 0; mf < 2; mf++)
#pragma unroll
      for (int nf = 0; nf < 2; nf++)
        acc[mf][nf] = MFMA16(a[mf], b[nf], acc[mf][nf]);

    asm volatile("s_waitcnt lgkmcnt(0)" ::: "memory");
    __builtin_amdgcn_s_barrier();
  }
#undef PSTAGE

#pragma unroll
  for (int mf = 0; mf < 2; mf++) {
#pragma unroll
    for (int r = 0; r < 4; r++) {
      int row = am0 + wr + mf * 16 + (lane >> 4) * 4 + r;
#pragma unroll
      for (int nf = 0; nf < 2; nf++) {
        int col = bn0 + wc + nf * 16 + (lane & 15);
        C[(size_t)row * N + col] = acc[mf][nf][r];
      }
    }
  }
}

// ---------------- causal flash attention (round-15 proven: 62.8 us) ----------------
// 4 waves/block; heavy/light q32-tile pairing (equal-duration blocks).
// KVBLK=64, K/Vt TRIPLE-buffered LDS (slot-XOR swizzle), 2-tile-deep
// counted-vmcnt prefetch, ONE barrier per tile. exp2-domain softmax, no max
// tracking, lsum via ones-row MFMA, P packed by truncation + permlane.
__global__ __launch_bounds__(256) void attn_kernel(
    const short* __restrict__ qk, const short* __restrict__ Vt,
    short* __restrict__ yb) {
  __shared__ short Ks[3][64 * 64];
  __shared__ short Vs[3][64 * 64];

  const int tid  = threadIdx.x;
  const int lane = tid & 63;
  const int wv   = tid >> 6;
  const int col  = lane & 15;
  const int g    = lane >> 4;

  const int bid = blockIdx.x;
  const int h   = bid % NH;
  const int pr  = bid / NH;            // 0..63, 0 = heaviest pair
  const int myi = (wv < 2) ? (127 - pr) : pr;   // q32-tile index
  const int qw  = myi * 32 + (wv & 1) * 16;     // this wave's 16 q rows
  const int nt  = ((127 - pr) * 32 + 31) / 64 + 1;  // block tile count (heavy)

  const int hq = h * HD;
  const int hk = C_DIM + h * HD;
  const short* Vth = Vt + (size_t)h * HD * T_SEQ;

  const int sidx0 = tid;
  const int sidx1 = 256 + tid;
  const int srow0 = sidx0 >> 3, sslot0 = (sidx0 & 7) ^ (srow0 & 7);
  const int srow1 = sidx1 >> 3, sslot1 = (sidx1 & 7) ^ (srow1 & 7);

#define STAGE(buf, kvoff)                                                               \
  do {                                                                                  \
    __builtin_amdgcn_global_load_lds(                                                   \
        (const __attribute__((address_space(1))) void*)(qk + (size_t)((kvoff) + srow0) * QK_N + hk + sslot0 * 8), \
        (__attribute__((address_space(3))) void*)(&Ks[buf][sidx0 * 8]), 16, 0, 0);      \
    __builtin_amdgcn_global_load_lds(                                                   \
        (const __attribute__((address_space(1))) void*)(qk + (size_t)((kvoff) + srow1) * QK_N + hk + sslot1 * 8), \
        (__attribute__((address_space(3))) void*)(&Ks[buf][sidx1 * 8]), 16, 0, 0);      \
    __builtin_amdgcn_global_load_lds(                                                   \
        (const __attribute__((address_space(1))) void*)(Vth + (size_t)srow0 * T_SEQ + (kvoff) + sslot0 * 8), \
        (__attribute__((address_space(3))) void*)(&Vs[buf][sidx0 * 8]), 16, 0, 0);      \
    __builtin_amdgcn_global_load_lds(                                                   \
        (const __attribute__((address_space(1))) void*)(Vth + (size_t)srow1 * T_SEQ + (kvoff) + sslot1 * 8), \
        (__attribute__((address_space(3))) void*)(&Vs[buf][sidx1 * 8]), 16, 0, 0);      \
  } while (0)

  // Q fragments (pre-scaled): qf[hf] = Q[qw+col][hf*32 + g*8 + j]
  bfx8 qf[2];
#pragma unroll
  for (int hf = 0; hf < 2; hf++)
    qf[hf] = *(const bfx8*)&qk[(size_t)(qw + col) * QK_N + hq + hf * 32 + g * 8];

  // hoisted LDS read offsets (loop-invariant; row&7 == col&7)
  int koff[4][2], voff[2][4];
#pragma unroll
  for (int sub = 0; sub < 4; sub++) {
    int row = sub * 16 + col;
#pragma unroll
    for (int hf = 0; hf < 2; hf++)
      koff[sub][hf] = row * 64 + ((((hf << 2) | g) ^ (row & 7)) * 8);
  }
#pragma unroll
  for (int ks = 0; ks < 2; ks++)
#pragma unroll
    for (int c = 0; c < 4; c++) {
      int row = c * 16 + col;
      voff[ks][c] = row * 64 + ((((ks << 2) | g) ^ (row & 7)) * 8);
    }

  bfx8 ones;
#pragma unroll
  for (int j = 0; j < 8; j++) ones[j] = (short)0x3F80;  // bf16 1.0

  const f32x4 zero = {0.f, 0.f, 0.f, 0.f};
  f32x4 o[4];
#pragma unroll
  for (int c = 0; c < 4; c++) o[c] = zero;
  f32x4 o_l = zero;  // lsum accumulator

  const int qabs = qw + col;

#define TILE_BODY(BUF, KV)                                                              \
  do {                                                                                  \
    if ((KV) <= qw + 15) {                                                              \
      bfx8 kf[4][2];                                                                    \
      _Pragma("unroll") for (int sub = 0; sub < 4; sub++)                               \
          _Pragma("unroll") for (int hf = 0; hf < 2; hf++)                              \
              kf[sub][hf] = *(const bfx8*)&Ks[BUF][koff[sub][hf]];                      \
      bfx8 vtf[2][4];                                                                   \
      _Pragma("unroll") for (int ks = 0; ks < 2; ks++)                                  \
          _Pragma("unroll") for (int c = 0; c < 4; c++)                                 \
              vtf[ks][c] = *(const bfx8*)&Vs[BUF][voff[ks][c]];                         \
      f32x4 s[4];                                                                       \
      __builtin_amdgcn_s_setprio(1);                                                    \
      _Pragma("unroll") for (int sub = 0; sub < 4; sub++) {                             \
        s[sub] = zero;                                                                  \
        s[sub] = MFMA16(kf[sub][0], qf[0], s[sub]);                                     \
        s[sub] = MFMA16(kf[sub][1], qf[1], s[sub]);                                     \
      }                                                                                 \
      __builtin_amdgcn_s_setprio(0);                                                    \
      if (!((KV) + 63 <= qw)) {                                                         \
        _Pragma("unroll") for (int sub = 0; sub < 4; sub++)                             \
            _Pragma("unroll") for (int r = 0; r < 4; r++) {                             \
              int key = (KV) + sub * 16 + 4 * g + r;                                    \
              if (key > qabs) s[sub][r] = -INFINITY;                                    \
            }                                                                           \
      }                                                                                 \
      float p[4][4];                                                                    \
      _Pragma("unroll") for (int sub = 0; sub < 4; sub++)                               \
          _Pragma("unroll") for (int r = 0; r < 4; r++)                                 \
              p[sub][r] = EXP2(s[sub][r]);                                              \
      _Pragma("unroll") for (int ks = 0; ks < 2; ks++) {                                \
        unsigned x0 = packtrunc(p[2 * ks][0], p[2 * ks][1]);                            \
        unsigned y0 = packtrunc(p[2 * ks + 1][0], p[2 * ks + 1][1]);                    \
        unsigned x1 = packtrunc(p[2 * ks][2], p[2 * ks][3]);                            \
        unsigned y1 = packtrunc(p[2 * ks + 1][2], p[2 * ks + 1][3]);                    \
        pl32(x0, y0); pl16(x0, y0);                                                     \
        pl32(x1, y1); pl16(x1, y1);                                                     \
        u32x4 w; w[0] = x0; w[1] = x1; w[2] = y0; w[3] = y1;                            \
        bfx8 pf = __builtin_bit_cast(bfx8, w);                                          \
        __builtin_amdgcn_s_setprio(1);                                                  \
        _Pragma("unroll") for (int c = 0; c < 4; c++)                                   \
            o[c] = MFMA16(vtf[ks][c], pf, o[c]);                                        \
        o_l = MFMA16(ones, pf, o_l);                                                    \
        __builtin_amdgcn_s_setprio(0);                                                  \
      }                                                                                 \
    }                                                                                   \
  } while (0)

#define PHASE(BCUR, BNXT2)                                                              \
  do {                                                                                  \
    if (t + 1 < nt) { asm volatile("s_waitcnt vmcnt(4)" ::: "memory"); }                \
    else            { asm volatile("s_waitcnt vmcnt(0)" ::: "memory"); }                \
    __builtin_amdgcn_s_barrier();                                                       \
    if (t + 2 < nt) STAGE(BNXT2, (t + 2) * 64);                                         \
    TILE_BODY(BCUR, t * 64);                                                            \
    asm volatile("s_waitcnt lgkmcnt(0)" ::: "memory");                                  \
  } while (0)

  STAGE(0, 0);
  STAGE(1, 64);  // nt >= 33 always

  int t = 0;
  while (true) {
    PHASE(0, 2); if (++t >= nt) break;
    PHASE(1, 0); if (++t >= nt) break;
    PHASE(2, 1); if (++t >= nt) break;
  }

  float inv = 1.f / o_l[0];
#pragma unroll
  for (int c = 0; c < 4; c++) {
    bfx4 ov;
#pragma unroll
    for (int r = 0; r < 4; r++) ov[r] = f2bf(o[c][r] * inv);
    *(bfx4*)&yb[(size_t)(qw + col) * C_DIM + h * HD + c * 16 + g * 4] = ov;
  }
#undef PHASE
#undef TILE_BODY
#undef STAGE
}

// ---------------- launch ----------------
extern "C" void kernel_launch(void* const* d_in, const int* in_sizes, int n_in,
                              void* d_out, int out_size, void* d_ws, size_t ws_size,
                              hipStream_t stream) {
  const float* x      = (const float*)d_in[0];
  const float* w_attn = (const float*)d_in[1];
  const float* w_proj = (const float*)d_in[2];
  float* out = (float*)d_out;

  char* ws = (char*)d_ws;
  short* xb  = (short*)(ws);                       // 6291456 B
  short* wab = (short*)(ws + 6291456);             // 3538944 B
  short* wpb = (short*)(ws + 9830400);             // 1179648 B
  short* qk  = (short*)(ws + 11010048);            // 4096*1536*2 = 12582912 B
  short* Vt  = (short*)(ws + 23592960);            // 768*4096*2  = 6291456 B
  short* yb  = (short*)(ws + 29884416);            // 6291456 B (end 36175872)

  prep_kernel<<<NB_CONV + NB_TA + NB_TB, 256, 0, stream>>>(x, xb, w_attn, wab, w_proj, wpb);
  gemm_qkv<<<dim3(T_SEQ / 128, QKV_N / 96), 256, 0, stream>>>(xb, wab, qk, Vt, C_DIM);
  attn_kernel<<<64 * NH, 256, 0, stream>>>(qk, Vt, yb);
  gemm_proj<<<dim3(T_SEQ / 64, C_DIM / 64), 256, 0, stream>>>(yb, wpb, out, C_DIM, C_DIM);
}

// Round 18
// 105.134 us; speedup vs baseline: 1.1030x; 1.1030x over previous
//
#include <hip/hip_runtime.h>
#include <hip/hip_bf16.h>

typedef __attribute__((ext_vector_type(8))) short bfx8;
typedef __attribute__((ext_vector_type(4))) short bfx4;
typedef __attribute__((ext_vector_type(4))) float f32x4;
typedef __attribute__((ext_vector_type(4))) unsigned int u32x4;
typedef __attribute__((ext_vector_type(2))) unsigned int u32x2;

#define T_SEQ 4096
#define C_DIM 768
#define NH    12
#define HD    64
#define QKV_N 2304
#define QK_N  1536

#define MFMA16(a, b, c) __builtin_amdgcn_mfma_f32_16x16x32_bf16((a), (b), (c), 0, 0, 0)

#if __has_builtin(__builtin_amdgcn_exp2f)
#define EXP2(x) __builtin_amdgcn_exp2f(x)
#else
#define EXP2(x) exp2f(x)
#endif

__device__ __forceinline__ short f2bf(float f) {
  __hip_bfloat16 h = __float2bfloat16(f);
  return __builtin_bit_cast(short, h);
}

// pack two f32 -> u32 of 2 bf16 (truncation): (hi16(odd)<<16)|hi16(even), 1 op
__device__ __forceinline__ unsigned packtrunc(float p_even, float p_odd) {
#if __has_builtin(__builtin_amdgcn_perm)
  return __builtin_amdgcn_perm(__builtin_bit_cast(unsigned, p_odd),
                               __builtin_bit_cast(unsigned, p_even), 0x07060302u);
#else
  return (__builtin_bit_cast(unsigned, p_odd) & 0xFFFF0000u) |
         (__builtin_bit_cast(unsigned, p_even) >> 16);
#endif
}

// permlane swaps via builtins (hazard-safe); used ONLY for P-redistribution.
__device__ __forceinline__ void pl16(unsigned& a, unsigned& b) {
#if __has_builtin(__builtin_amdgcn_permlane16_swap)
  u32x2 r = __builtin_amdgcn_permlane16_swap(a, b, false, false);
  a = r[0]; b = r[1];
#else
  unsigned ax = (unsigned)__shfl_xor((int)a, 16, 64);
  unsigned bx = (unsigned)__shfl_xor((int)b, 16, 64);
  bool odd = ((threadIdx.x >> 4) & 1) != 0;
  unsigned na = odd ? bx : a;
  unsigned nb = odd ? b : ax;
  a = na; b = nb;
#endif
}
__device__ __forceinline__ void pl32(unsigned& a, unsigned& b) {
#if __has_builtin(__builtin_amdgcn_permlane32_swap)
  u32x2 r = __builtin_amdgcn_permlane32_swap(a, b, false, false);
  a = r[0]; b = r[1];
#else
  unsigned ax = (unsigned)__shfl_xor((int)a, 32, 64);
  unsigned bx = (unsigned)__shfl_xor((int)b, 32, 64);
  bool hi = ((threadIdx.x >> 5) & 1) != 0;
  unsigned na = hi ? bx : a;
  unsigned nb = hi ? b : ax;
  a = na; b = nb;
#endif
}

// ---------------- fused prep: x->bf16 | w_attn^T (Q-scaled) | w_proj^T ----------------
#define NB_CONV 3072
#define NB_TA   (72 * 24)
#define NB_TB   (24 * 24)
__global__ __launch_bounds__(256) void prep_kernel(
    const float* __restrict__ x, short* __restrict__ xb,
    const float* __restrict__ w_attn, short* __restrict__ wab,
    const float* __restrict__ w_proj, short* __restrict__ wpb) {
  __shared__ short tile[32][33];
  const int b = blockIdx.x;
  if (b < NB_CONV) {
    int i = b * 256 + threadIdx.x;
    float4 v = ((const float4*)x)[i];
    bfx4 o;
    o[0] = f2bf(v.x); o[1] = f2bf(v.y); o[2] = f2bf(v.z); o[3] = f2bf(v.w);
    ((bfx4*)xb)[i] = o;
    return;
  }
  const float* in; short* out; int Cc, bx, by, qcols;
  if (b < NB_CONV + NB_TA) {
    int bb = b - NB_CONV;
    in = w_attn; out = wab; Cc = QKV_N;
    bx = (bb % 72) * 32; by = (bb / 72) * 32;
    qcols = C_DIM;  // scale Q columns by 0.125*log2(e)
  } else {
    int bb = b - NB_CONV - NB_TA;
    in = w_proj; out = wpb; Cc = C_DIM;
    bx = (bb % 24) * 32; by = (bb / 24) * 32;
    qcols = 0;
  }
  int tx = threadIdx.x & 31, ty = threadIdx.x >> 5;  // 32x8
  float sc = (bx + tx) < qcols ? 0.125f * 1.4426950408889634f : 1.0f;
#pragma unroll
  for (int i = 0; i < 32; i += 8)
    tile[ty + i][tx] = f2bf(in[(size_t)(by + ty + i) * Cc + (bx + tx)] * sc);
  __syncthreads();
#pragma unroll
  for (int i = 0; i < 32; i += 8)
    out[(size_t)(bx + ty + i) * C_DIM + (by + tx)] = tile[tx][ty + i];
}

// ---------------- bf16 GEMM (128x96, BK=32): QKV with fused V-transpose ----------------
// Round-12-proven lockstep schedule (double-buffer, 1-deep prefetch, two
// barriers/K-step), BM=128 BN=96 -> grid 32x24 = 768 = 3/CU. B staged padded
// to 128 rows (rows>=96 clamp-duplicate row 95, never read). Wave 64x48.
__global__ __launch_bounds__(256) void gemm_qkv(
    const short* __restrict__ A, const short* __restrict__ Bt,
    short* __restrict__ qk, short* __restrict__ Vt, int K) {
  __shared__ short As[2][128 * 32];
  __shared__ short Bs[2][128 * 32];
  const int tid  = threadIdx.x;
  const int lane = tid & 63;
  const int wave = tid >> 6;
  const int am0 = blockIdx.x * 128;
  const int bn0 = blockIdx.y * 96;
  const int wr = (wave >> 1) * 64;
  const int wc = (wave & 1) * 48;

  const int idx0 = tid,       r0 = idx0 >> 2, c0 = (idx0 & 3) * 8;
  const int idx1 = 256 + tid, r1 = idx1 >> 2, c1 = (idx1 & 3) * 8;
  const int rb0 = (r0 < 96) ? r0 : 95;   // B row clamp (pad rows duplicate 95)
  const int rb1 = (r1 < 96) ? r1 : 95;

#define GSTAGE(buf, k0)                                                                 \
  do {                                                                                  \
    __builtin_amdgcn_global_load_lds(                                                   \
        (const __attribute__((address_space(1))) void*)(A + (size_t)(am0 + r0) * K + (k0) + c0), \
        (__attribute__((address_space(3))) void*)(&As[buf][idx0 * 8]), 16, 0, 0);       \
    __builtin_amdgcn_global_load_lds(                                                   \
        (const __attribute__((address_space(1))) void*)(A + (size_t)(am0 + r1) * K + (k0) + c1), \
        (__attribute__((address_space(3))) void*)(&As[buf][idx1 * 8]), 16, 0, 0);       \
    __builtin_amdgcn_global_load_lds(                                                   \
        (const __attribute__((address_space(1))) void*)(Bt + (size_t)(bn0 + rb0) * K + (k0) + c0), \
        (__attribute__((address_space(3))) void*)(&Bs[buf][idx0 * 8]), 16, 0, 0);       \
    __builtin_amdgcn_global_load_lds(                                                   \
        (const __attribute__((address_space(1))) void*)(Bt + (size_t)(bn0 + rb1) * K + (k0) + c1), \
        (__attribute__((address_space(3))) void*)(&Bs[buf][idx1 * 8]), 16, 0, 0);       \
  } while (0)

  const f32x4 zero = {0.f, 0.f, 0.f, 0.f};
  f32x4 acc[4][3];
#pragma unroll
  for (int i = 0; i < 4; i++)
#pragma unroll
    for (int j = 0; j < 3; j++) acc[i][j] = zero;

  const int aoff = (wr + (lane & 15)) * 32 + (lane >> 4) * 8;
  const int boff = (wc + (lane & 15)) * 32 + (lane >> 4) * 8;

  const int nk = K / 32;
  GSTAGE(0, 0);
  for (int t = 0; t < nk; t++) {
    const int cur = t & 1;
    if (t + 1 < nk) {
      GSTAGE(cur ^ 1, (t + 1) * 32);
      asm volatile("s_waitcnt vmcnt(4)" ::: "memory");
    } else {
      asm volatile("s_waitcnt vmcnt(0)" ::: "memory");
    }
    __builtin_amdgcn_s_barrier();

    bfx8 a[4], b[3];
#pragma unroll
    for (int mf = 0; mf < 4; mf++)
      a[mf] = *(const bfx8*)&As[cur][aoff + mf * 16 * 32];
#pragma unroll
    for (int nf = 0; nf < 3; nf++)
      b[nf] = *(const bfx8*)&Bs[cur][boff + nf * 16 * 32];
#pragma unroll
    for (int mf = 0; mf < 4; mf++)
#pragma unroll
      for (int nf = 0; nf < 3; nf++)
        acc[mf][nf] = MFMA16(a[mf], b[nf], acc[mf][nf]);

    asm volatile("s_waitcnt lgkmcnt(0)" ::: "memory");
    __builtin_amdgcn_s_barrier();
  }
#undef GSTAGE

  if (bn0 >= QK_N) {
#pragma unroll
    for (int mf = 0; mf < 4; mf++) {
      int row0 = am0 + wr + mf * 16 + (lane >> 4) * 4;
#pragma unroll
      for (int nf = 0; nf < 3; nf++) {
        int colV = bn0 - QK_N + wc + nf * 16 + (lane & 15);
        bfx4 ov;
#pragma unroll
        for (int r = 0; r < 4; r++) ov[r] = f2bf(acc[mf][nf][r]);
        *(bfx4*)&Vt[(size_t)colV * T_SEQ + row0] = ov;
      }
    }
  } else {
#pragma unroll
    for (int mf = 0; mf < 4; mf++) {
#pragma unroll
      for (int r = 0; r < 4; r++) {
        int row = am0 + wr + mf * 16 + (lane >> 4) * 4 + r;
#pragma unroll
        for (int nf = 0; nf < 3; nf++) {
          int col = bn0 + wc + nf * 16 + (lane & 15);
          qk[(size_t)row * QK_N + col] = f2bf(acc[mf][nf][r]);
        }
      }
    }
  }
}

// ---------------- bf16 GEMM (64x64, f32 out): projection (round-12 proven) ----------------
__global__ __launch_bounds__(256) void gemm_proj(
    const short* __restrict__ A, const short* __restrict__ Bt,
    float* __restrict__ C, int N, int K) {
  __shared__ short As[2][64 * 32];
  __shared__ short Bs[2][64 * 32];
  const int tid  = threadIdx.x;
  const int lane = tid & 63;
  const int wave = tid >> 6;
  const int am0 = blockIdx.x * 64;
  const int bn0 = blockIdx.y * 64;
  const int wr = (wave >> 1) * 32;
  const int wc = (wave & 1) * 32;

  const int r0 = tid >> 2, c0 = (tid & 3) * 8;

#define PSTAGE(buf, k0)                                                                 \
  do {                                                                                  \
    __builtin_amdgcn_global_load_lds(                                                   \
        (const __attribute__((address_space(1))) void*)(A + (size_t)(am0 + r0) * K + (k0) + c0), \
        (__attribute__((address_space(3))) void*)(&As[buf][tid * 8]), 16, 0, 0);        \
    __builtin_amdgcn_global_load_lds(                                                   \
        (const __attribute__((address_space(1))) void*)(Bt + (size_t)(bn0 + r0) * K + (k0) + c0), \
        (__attribute__((address_space(3))) void*)(&Bs[buf][tid * 8]), 16, 0, 0);        \
  } while (0)

  const f32x4 zero = {0.f, 0.f, 0.f, 0.f};
  f32x4 acc[2][2];
#pragma unroll
  for (int i = 0; i < 2; i++)
#pragma unroll
    for (int j = 0; j < 2; j++) acc[i][j] = zero;

  const int aoff = (wr + (lane & 15)) * 32 + (lane >> 4) * 8;
  const int boff = (wc + (lane & 15)) * 32 + (lane >> 4) * 8;

  const int nk = K / 32;
  PSTAGE(0, 0);
  for (int t = 0; t < nk; t++) {
    const int cur = t & 1;
    if (t + 1 < nk) {
      PSTAGE(cur ^ 1, (t + 1) * 32);
      asm volatile("s_waitcnt vmcnt(2)" ::: "memory");
    } else {
      asm volatile("s_waitcnt vmcnt(0)" ::: "memory");
    }
    __builtin_amdgcn_s_barrier();

    bfx8 a[2], b[2];
#pragma unroll
    for (int mf = 0; mf < 2; mf++)
      a[mf] = *(const bfx8*)&As[cur][aoff + mf * 16 * 32];
#pragma unroll
    for (int nf = 0; nf < 2; nf++)
      b[nf] = *(const bfx8*)&Bs[cur][boff + nf * 16 * 32];
#pragma unroll
    for (int mf = 0; mf < 2; mf++)
#pragma unroll
      for (int nf = 0; nf < 2; nf++)
        acc[mf][nf] = MFMA16(a[mf], b[nf], acc[mf][nf]);

    asm volatile("s_waitcnt lgkmcnt(0)" ::: "memory");
    __builtin_amdgcn_s_barrier();
  }
#undef PSTAGE

#pragma unroll
  for (int mf = 0; mf < 2; mf++) {
#pragma unroll
    for (int r = 0; r < 4; r++) {
      int row = am0 + wr + mf * 16 + (lane >> 4) * 4 + r;
#pragma unroll
      for (int nf = 0; nf < 2; nf++) {
        int col = bn0 + wc + nf * 16 + (lane & 15);
        C[(size_t)row * N + col] = acc[mf][nf][r];
      }
    }
  }
}

// ---------------- causal flash attention (round-13/15 proven: 62.8 us) ----------------
// 4 waves/block; heavy/light q32-tile pairing (equal-duration blocks).
// KVBLK=64, K/Vt TRIPLE-buffered LDS (slot-XOR swizzle), 2-tile-deep
// counted-vmcnt prefetch, ONE barrier per tile. exp2-domain softmax, no max
// tracking, lsum via ones-row MFMA, P packed by truncation + permlane.
__global__ __launch_bounds__(256) void attn_kernel(
    const short* __restrict__ qk, const short* __restrict__ Vt,
    short* __restrict__ yb) {
  __shared__ short Ks[3][64 * 64];
  __shared__ short Vs[3][64 * 64];

  const int tid  = threadIdx.x;
  const int lane = tid & 63;
  const int wv   = tid >> 6;
  const int col  = lane & 15;
  const int g    = lane >> 4;

  const int bid = blockIdx.x;
  const int h   = bid % NH;
  const int pr  = bid / NH;            // 0..63, 0 = heaviest pair
  const int myi = (wv < 2) ? (127 - pr) : pr;   // q32-tile index
  const int qw  = myi * 32 + (wv & 1) * 16;     // this wave's 16 q rows
  const int nt  = ((127 - pr) * 32 + 31) / 64 + 1;  // block tile count (heavy)

  const int hq = h * HD;
  const int hk = C_DIM + h * HD;
  const short* Vth = Vt + (size_t)h * HD * T_SEQ;

  const int sidx0 = tid;
  const int sidx1 = 256 + tid;
  const int srow0 = sidx0 >> 3, sslot0 = (sidx0 & 7) ^ (srow0 & 7);
  const int srow1 = sidx1 >> 3, sslot1 = (sidx1 & 7) ^ (srow1 & 7);

#define STAGE(buf, kvoff)                                                               \
  do {                                                                                  \
    __builtin_amdgcn_global_load_lds(                                                   \
        (const __attribute__((address_space(1))) void*)(qk + (size_t)((kvoff) + srow0) * QK_N + hk + sslot0 * 8), \
        (__attribute__((address_space(3))) void*)(&Ks[buf][sidx0 * 8]), 16, 0, 0);      \
    __builtin_amdgcn_global_load_lds(                                                   \
        (const __attribute__((address_space(1))) void*)(qk + (size_t)((kvoff) + srow1) * QK_N + hk + sslot1 * 8), \
        (__attribute__((address_space(3))) void*)(&Ks[buf][sidx1 * 8]), 16, 0, 0);      \
    __builtin_amdgcn_global_load_lds(                                                   \
        (const __attribute__((address_space(1))) void*)(Vth + (size_t)srow0 * T_SEQ + (kvoff) + sslot0 * 8), \
        (__attribute__((address_space(3))) void*)(&Vs[buf][sidx0 * 8]), 16, 0, 0);      \
    __builtin_amdgcn_global_load_lds(                                                   \
        (const __attribute__((address_space(1))) void*)(Vth + (size_t)srow1 * T_SEQ + (kvoff) + sslot1 * 8), \
        (__attribute__((address_space(3))) void*)(&Vs[buf][sidx1 * 8]), 16, 0, 0);      \
  } while (0)

  // Q fragments (pre-scaled): qf[hf] = Q[qw+col][hf*32 + g*8 + j]
  bfx8 qf[2];
#pragma unroll
  for (int hf = 0; hf < 2; hf++)
    qf[hf] = *(const bfx8*)&qk[(size_t)(qw + col) * QK_N + hq + hf * 32 + g * 8];

  // hoisted LDS read offsets (loop-invariant; row&7 == col&7)
  int koff[4][2], voff[2][4];
#pragma unroll
  for (int sub = 0; sub < 4; sub++) {
    int row = sub * 16 + col;
#pragma unroll
    for (int hf = 0; hf < 2; hf++)
      koff[sub][hf] = row * 64 + ((((hf << 2) | g) ^ (row & 7)) * 8);
  }
#pragma unroll
  for (int ks = 0; ks < 2; ks++)
#pragma unroll
    for (int c = 0; c < 4; c++) {
      int row = c * 16 + col;
      voff[ks][c] = row * 64 + ((((ks << 2) | g) ^ (row & 7)) * 8);
    }

  bfx8 ones;
#pragma unroll
  for (int j = 0; j < 8; j++) ones[j] = (short)0x3F80;  // bf16 1.0

  const f32x4 zero = {0.f, 0.f, 0.f, 0.f};
  f32x4 o[4];
#pragma unroll
  for (int c = 0; c < 4; c++) o[c] = zero;
  f32x4 o_l = zero;  // lsum accumulator

  const int qabs = qw + col;

#define TILE_BODY(BUF, KV)                                                              \
  do {                                                                                  \
    if ((KV) <= qw + 15) {                                                              \
      bfx8 kf[4][2];                                                                    \
      _Pragma("unroll") for (int sub = 0; sub < 4; sub++)                               \
          _Pragma("unroll") for (int hf = 0; hf < 2; hf++)                              \
              kf[sub][hf] = *(const bfx8*)&Ks[BUF][koff[sub][hf]];                      \
      bfx8 vtf[2][4];                                                                   \
      _Pragma("unroll") for (int ks = 0; ks < 2; ks++)                                  \
          _Pragma("unroll") for (int c = 0; c < 4; c++)                                 \
              vtf[ks][c] = *(const bfx8*)&Vs[BUF][voff[ks][c]];                         \
      f32x4 s[4];                                                                       \
      __builtin_amdgcn_s_setprio(1);                                                    \
      _Pragma("unroll") for (int sub = 0; sub < 4; sub++) {                             \
        s[sub] = zero;                                                                  \
        s[sub] = MFMA16(kf[sub][0], qf[0], s[sub]);                                     \
        s[sub] = MFMA16(kf[sub][1], qf[1], s[sub]);                                     \
      }                                                                                 \
      __builtin_amdgcn_s_setprio(0);                                                    \
      if (!((KV) + 63 <= qw)) {                                                         \
        _Pragma("unroll") for (int sub = 0; sub < 4; sub++)                             \
            _Pragma("unroll") for (int r = 0; r < 4; r++) {                             \
              int key = (KV) + sub * 16 + 4 * g + r;                                    \
              if (key > qabs) s[sub][r] = -INFINITY;                                    \
            }                                                                           \
      }                                                                                 \
      float p[4][4];                                                                    \
      _Pragma("unroll") for (int sub = 0; sub < 4; sub++)                               \
          _Pragma("unroll") for (int r = 0; r < 4; r++)                                 \
              p[sub][r] = EXP2(s[sub][r]);                                              \
      _Pragma("unroll") for (int ks = 0; ks < 2; ks++) {                                \
        unsigned x0 = packtrunc(p[2 * ks][0], p[2 * ks][1]);                            \
        unsigned y0 = packtrunc(p[2 * ks + 1][0], p[2 * ks + 1][1]);                    \
        unsigned x1 = packtrunc(p[2 * ks][2], p[2 * ks][3]);                            \
        unsigned y1 = packtrunc(p[2 * ks + 1][2], p[2 * ks + 1][3]);                    \
        pl32(x0, y0); pl16(x0, y0);                                                     \
        pl32(x1, y1); pl16(x1, y1);                                                     \
        u32x4 w; w[0] = x0; w[1] = x1; w[2] = y0; w[3] = y1;                            \
        bfx8 pf = __builtin_bit_cast(bfx8, w);                                          \
        __builtin_amdgcn_s_setprio(1);                                                  \
        _Pragma("unroll") for (int c = 0; c < 4; c++)                                   \
            o[c] = MFMA16(vtf[ks][c], pf, o[c]);                                        \
        o_l = MFMA16(ones, pf, o_l);                                                    \
        __builtin_amdgcn_s_setprio(0);                                                  \
      }                                                                                 \
    }                                                                                   \
  } while (0)

#define PHASE(BCUR, BNXT2)                                                              \
  do {                                                                                  \
    if (t + 1 < nt) { asm volatile("s_waitcnt vmcnt(4)" ::: "memory"); }                \
    else            { asm volatile("s_waitcnt vmcnt(0)" ::: "memory"); }                \
    __builtin_amdgcn_s_barrier();                                                       \
    if (t + 2 < nt) STAGE(BNXT2, (t + 2) * 64);                                         \
    TILE_BODY(BCUR, t * 64);                                                            \
    asm volatile("s_waitcnt lgkmcnt(0)" ::: "memory");                                  \
  } while (0)

  STAGE(0, 0);
  STAGE(1, 64);  // nt >= 33 always

  int t = 0;
  while (true) {
    PHASE(0, 2); if (++t >= nt) break;
    PHASE(1, 0); if (++t >= nt) break;
    PHASE(2, 1); if (++t >= nt) break;
  }

  float inv = 1.f / o_l[0];
#pragma unroll
  for (int c = 0; c < 4; c++) {
    bfx4 ov;
#pragma unroll
    for (int r = 0; r < 4; r++) ov[r] = f2bf(o[c][r] * inv);
    *(bfx4*)&yb[(size_t)(qw + col) * C_DIM + h * HD + c * 16 + g * 4] = ov;
  }
#undef PHASE
#undef TILE_BODY
#undef STAGE
}

// ---------------- launch ----------------
extern "C" void kernel_launch(void* const* d_in, const int* in_sizes, int n_in,
                              void* d_out, int out_size, void* d_ws, size_t ws_size,
                              hipStream_t stream) {
  const float* x      = (const float*)d_in[0];
  const float* w_attn = (const float*)d_in[1];
  const float* w_proj = (const float*)d_in[2];
  float* out = (float*)d_out;

  char* ws = (char*)d_ws;
  short* xb  = (short*)(ws);                       // 6291456 B
  short* wab = (short*)(ws + 6291456);             // 3538944 B
  short* wpb = (short*)(ws + 9830400);             // 1179648 B
  short* qk  = (short*)(ws + 11010048);            // 4096*1536*2 = 12582912 B
  short* Vt  = (short*)(ws + 23592960);            // 768*4096*2  = 6291456 B
  short* yb  = (short*)(ws + 29884416);            // 6291456 B (end 36175872)

  prep_kernel<<<NB_CONV + NB_TA + NB_TB, 256, 0, stream>>>(x, xb, w_attn, wab, w_proj, wpb);
  gemm_qkv<<<dim3(T_SEQ / 128, QKV_N / 96), 256, 0, stream>>>(xb, wab, qk, Vt, C_DIM);
  attn_kernel<<<64 * NH, 256, 0, stream>>>(qk, Vt, yb);
  gemm_proj<<<dim3(T_SEQ / 64, C_DIM / 64), 256, 0, stream>>>(yb, wpb, out, C_DIM, C_DIM);
}

// Round 19
// 100.286 us; speedup vs baseline: 1.1563x; 1.0483x over previous
//
#include <hip/hip_runtime.h>
#include <hip/hip_bf16.h>

typedef __attribute__((ext_vector_type(8))) short bfx8;
typedef __attribute__((ext_vector_type(4))) short bfx4;
typedef __attribute__((ext_vector_type(4))) float f32x4;
typedef __attribute__((ext_vector_type(4))) unsigned int u32x4;
typedef __attribute__((ext_vector_type(2))) unsigned int u32x2;

#define T_SEQ 4096
#define C_DIM 768
#define NH    12
#define HD    64
#define QKV_N 2304
#define QK_N  1536

#define MFMA16(a, b, c) __builtin_amdgcn_mfma_f32_16x16x32_bf16((a), (b), (c), 0, 0, 0)

#if __has_builtin(__builtin_amdgcn_exp2f)
#define EXP2(x) __builtin_amdgcn_exp2f(x)
#else
#define EXP2(x) exp2f(x)
#endif

__device__ __forceinline__ short f2bf(float f) {
  __hip_bfloat16 h = __float2bfloat16(f);
  return __builtin_bit_cast(short, h);
}
__device__ __forceinline__ float bf2f(short s) {
  unsigned u = ((unsigned)(unsigned short)s) << 16;
  return __builtin_bit_cast(float, u);
}

// pack two f32 -> u32 of 2 bf16 (truncation): (hi16(odd)<<16)|hi16(even), 1 op
__device__ __forceinline__ unsigned packtrunc(float p_even, float p_odd) {
#if __has_builtin(__builtin_amdgcn_perm)
  return __builtin_amdgcn_perm(__builtin_bit_cast(unsigned, p_odd),
                               __builtin_bit_cast(unsigned, p_even), 0x07060302u);
#else
  return (__builtin_bit_cast(unsigned, p_odd) & 0xFFFF0000u) |
         (__builtin_bit_cast(unsigned, p_even) >> 16);
#endif
}

// permlane swaps via builtins (hazard-safe); used ONLY for P-redistribution.
__device__ __forceinline__ void pl16(unsigned& a, unsigned& b) {
#if __has_builtin(__builtin_amdgcn_permlane16_swap)
  u32x2 r = __builtin_amdgcn_permlane16_swap(a, b, false, false);
  a = r[0]; b = r[1];
#else
  unsigned ax = (unsigned)__shfl_xor((int)a, 16, 64);
  unsigned bx = (unsigned)__shfl_xor((int)b, 16, 64);
  bool odd = ((threadIdx.x >> 4) & 1) != 0;
  unsigned na = odd ? bx : a;
  unsigned nb = odd ? b : ax;
  a = na; b = nb;
#endif
}
__device__ __forceinline__ void pl32(unsigned& a, unsigned& b) {
#if __has_builtin(__builtin_amdgcn_permlane32_swap)
  u32x2 r = __builtin_amdgcn_permlane32_swap(a, b, false, false);
  a = r[0]; b = r[1];
#else
  unsigned ax = (unsigned)__shfl_xor((int)a, 32, 64);
  unsigned bx = (unsigned)__shfl_xor((int)b, 32, 64);
  bool hi = ((threadIdx.x >> 5) & 1) != 0;
  unsigned na = hi ? bx : a;
  unsigned nb = hi ? b : ax;
  a = na; b = nb;
#endif
}

// ---------------- fused prep: x->bf16 | w_attn^T (Q-scaled) | w_proj^T ----------------
#define NB_CONV 3072
#define NB_TA   (72 * 24)
#define NB_TB   (24 * 24)
__global__ __launch_bounds__(256) void prep_kernel(
    const float* __restrict__ x, short* __restrict__ xb,
    const float* __restrict__ w_attn, short* __restrict__ wab,
    const float* __restrict__ w_proj, short* __restrict__ wpb) {
  __shared__ short tile[32][33];
  const int b = blockIdx.x;
  if (b < NB_CONV) {
    int i = b * 256 + threadIdx.x;
    float4 v = ((const float4*)x)[i];
    bfx4 o;
    o[0] = f2bf(v.x); o[1] = f2bf(v.y); o[2] = f2bf(v.z); o[3] = f2bf(v.w);
    ((bfx4*)xb)[i] = o;
    return;
  }
  const float* in; short* out; int Cc, bx, by, qcols;
  if (b < NB_CONV + NB_TA) {
    int bb = b - NB_CONV;
    in = w_attn; out = wab; Cc = QKV_N;
    bx = (bb % 72) * 32; by = (bb / 72) * 32;
    qcols = C_DIM;  // scale Q columns by 0.125*log2(e)
  } else {
    int bb = b - NB_CONV - NB_TA;
    in = w_proj; out = wpb; Cc = C_DIM;
    bx = (bb % 24) * 32; by = (bb / 24) * 32;
    qcols = 0;
  }
  int tx = threadIdx.x & 31, ty = threadIdx.x >> 5;  // 32x8
  float sc = (bx + tx) < qcols ? 0.125f * 1.4426950408889634f : 1.0f;
#pragma unroll
  for (int i = 0; i < 32; i += 8)
    tile[ty + i][tx] = f2bf(in[(size_t)(by + ty + i) * Cc + (bx + tx)] * sc);
  __syncthreads();
#pragma unroll
  for (int i = 0; i < 32; i += 8)
    out[(size_t)(bx + ty + i) * C_DIM + (by + tx)] = tile[tx][ty + i];
}

// ---------------- bf16 GEMM (128x96, BK=32): QKV with fused V-transpose ----------------
__global__ __launch_bounds__(256) void gemm_qkv(
    const short* __restrict__ A, const short* __restrict__ Bt,
    short* __restrict__ qk, short* __restrict__ Vt, int K) {
  __shared__ short As[2][128 * 32];
  __shared__ short Bs[2][128 * 32];
  const int tid  = threadIdx.x;
  const int lane = tid & 63;
  const int wave = tid >> 6;
  const int am0 = blockIdx.x * 128;
  const int bn0 = blockIdx.y * 96;
  const int wr = (wave >> 1) * 64;
  const int wc = (wave & 1) * 48;

  const int idx0 = tid,       r0 = idx0 >> 2, c0 = (idx0 & 3) * 8;
  const int idx1 = 256 + tid, r1 = idx1 >> 2, c1 = (idx1 & 3) * 8;
  const int rb0 = (r0 < 96) ? r0 : 95;
  const int rb1 = (r1 < 96) ? r1 : 95;

#define GSTAGE(buf, k0)                                                                 \
  do {                                                                                  \
    __builtin_amdgcn_global_load_lds(                                                   \
        (const __attribute__((address_space(1))) void*)(A + (size_t)(am0 + r0) * K + (k0) + c0), \
        (__attribute__((address_space(3))) void*)(&As[buf][idx0 * 8]), 16, 0, 0);       \
    __builtin_amdgcn_global_load_lds(                                                   \
        (const __attribute__((address_space(1))) void*)(A + (size_t)(am0 + r1) * K + (k0) + c1), \
        (__attribute__((address_space(3))) void*)(&As[buf][idx1 * 8]), 16, 0, 0);       \
    __builtin_amdgcn_global_load_lds(                                                   \
        (const __attribute__((address_space(1))) void*)(Bt + (size_t)(bn0 + rb0) * K + (k0) + c0), \
        (__attribute__((address_space(3))) void*)(&Bs[buf][idx0 * 8]), 16, 0, 0);       \
    __builtin_amdgcn_global_load_lds(                                                   \
        (const __attribute__((address_space(1))) void*)(Bt + (size_t)(bn0 + rb1) * K + (k0) + c1), \
        (__attribute__((address_space(3))) void*)(&Bs[buf][idx1 * 8]), 16, 0, 0);       \
  } while (0)

  const f32x4 zero = {0.f, 0.f, 0.f, 0.f};
  f32x4 acc[4][3];
#pragma unroll
  for (int i = 0; i < 4; i++)
#pragma unroll
    for (int j = 0; j < 3; j++) acc[i][j] = zero;

  const int aoff = (wr + (lane & 15)) * 32 + (lane >> 4) * 8;
  const int boff = (wc + (lane & 15)) * 32 + (lane >> 4) * 8;

  const int nk = K / 32;
  GSTAGE(0, 0);
  for (int t = 0; t < nk; t++) {
    const int cur = t & 1;
    if (t + 1 < nk) {
      GSTAGE(cur ^ 1, (t + 1) * 32);
      asm volatile("s_waitcnt vmcnt(4)" ::: "memory");
    } else {
      asm volatile("s_waitcnt vmcnt(0)" ::: "memory");
    }
    __builtin_amdgcn_s_barrier();

    bfx8 a[4], b[3];
#pragma unroll
    for (int mf = 0; mf < 4; mf++)
      a[mf] = *(const bfx8*)&As[cur][aoff + mf * 16 * 32];
#pragma unroll
    for (int nf = 0; nf < 3; nf++)
      b[nf] = *(const bfx8*)&Bs[cur][boff + nf * 16 * 32];
#pragma unroll
    for (int mf = 0; mf < 4; mf++)
#pragma unroll
      for (int nf = 0; nf < 3; nf++)
        acc[mf][nf] = MFMA16(a[mf], b[nf], acc[mf][nf]);

    asm volatile("s_waitcnt lgkmcnt(0)" ::: "memory");
    __builtin_amdgcn_s_barrier();
  }
#undef GSTAGE

  if (bn0 >= QK_N) {
#pragma unroll
    for (int mf = 0; mf < 4; mf++) {
      int row0 = am0 + wr + mf * 16 + (lane >> 4) * 4;
#pragma unroll
      for (int nf = 0; nf < 3; nf++) {
        int colV = bn0 - QK_N + wc + nf * 16 + (lane & 15);
        bfx4 ov;
#pragma unroll
        for (int r = 0; r < 4; r++) ov[r] = f2bf(acc[mf][nf][r]);
        *(bfx4*)&Vt[(size_t)colV * T_SEQ + row0] = ov;
      }
    }
  } else {
#pragma unroll
    for (int mf = 0; mf < 4; mf++) {
#pragma unroll
      for (int r = 0; r < 4; r++) {
        int row = am0 + wr + mf * 16 + (lane >> 4) * 4 + r;
#pragma unroll
        for (int nf = 0; nf < 3; nf++) {
          int col = bn0 + wc + nf * 16 + (lane & 15);
          qk[(size_t)row * QK_N + col] = f2bf(acc[mf][nf][r]);
        }
      }
    }
  }
}

// ---------------- bf16 GEMM (64x64, f32 out): projection (round-12 proven) ----------------
__global__ __launch_bounds__(256) void gemm_proj(
    const short* __restrict__ A, const short* __restrict__ Bt,
    float* __restrict__ C, int N, int K) {
  __shared__ short As[2][64 * 32];
  __shared__ short Bs[2][64 * 32];
  const int tid  = threadIdx.x;
  const int lane = tid & 63;
  const int wave = tid >> 6;
  const int am0 = blockIdx.x * 64;
  const int bn0 = blockIdx.y * 64;
  const int wr = (wave >> 1) * 32;
  const int wc = (wave & 1) * 32;

  const int r0 = tid >> 2, c0 = (tid & 3) * 8;

#define PSTAGE(buf, k0)                                                                 \
  do {                                                                                  \
    __builtin_amdgcn_global_load_lds(                                                   \
        (const __attribute__((address_space(1))) void*)(A + (size_t)(am0 + r0) * K + (k0) + c0), \
        (__attribute__((address_space(3))) void*)(&As[buf][tid * 8]), 16, 0, 0);        \
    __builtin_amdgcn_global_load_lds(                                                   \
        (const __attribute__((address_space(1))) void*)(Bt + (size_t)(bn0 + r0) * K + (k0) + c0), \
        (__attribute__((address_space(3))) void*)(&Bs[buf][tid * 8]), 16, 0, 0);        \
  } while (0)

  const f32x4 zero = {0.f, 0.f, 0.f, 0.f};
  f32x4 acc[2][2];
#pragma unroll
  for (int i = 0; i < 2; i++)
#pragma unroll
    for (int j = 0; j < 2; j++) acc[i][j] = zero;

  const int aoff = (wr + (lane & 15)) * 32 + (lane >> 4) * 8;
  const int boff = (wc + (lane & 15)) * 32 + (lane >> 4) * 8;

  const int nk = K / 32;
  PSTAGE(0, 0);
  for (int t = 0; t < nk; t++) {
    const int cur = t & 1;
    if (t + 1 < nk) {
      PSTAGE(cur ^ 1, (t + 1) * 32);
      asm volatile("s_waitcnt vmcnt(2)" ::: "memory");
    } else {
      asm volatile("s_waitcnt vmcnt(0)" ::: "memory");
    }
    __builtin_amdgcn_s_barrier();

    bfx8 a[2], b[2];
#pragma unroll
    for (int mf = 0; mf < 2; mf++)
      a[mf] = *(const bfx8*)&As[cur][aoff + mf * 16 * 32];
#pragma unroll
    for (int nf = 0; nf < 2; nf++)
      b[nf] = *(const bfx8*)&Bs[cur][boff + nf * 16 * 32];
#pragma unroll
    for (int mf = 0; mf < 2; mf++)
#pragma unroll
      for (int nf = 0; nf < 2; nf++)
        acc[mf][nf] = MFMA16(a[mf], b[nf], acc[mf][nf]);

    asm volatile("s_waitcnt lgkmcnt(0)" ::: "memory");
    __builtin_amdgcn_s_barrier();
  }
#undef PSTAGE

#pragma unroll
  for (int mf = 0; mf < 2; mf++) {
#pragma unroll
    for (int r = 0; r < 4; r++) {
      int row = am0 + wr + mf * 16 + (lane >> 4) * 4 + r;
#pragma unroll
      for (int nf = 0; nf < 2; nf++) {
        int col = bn0 + wc + nf * 16 + (lane & 15);
        C[(size_t)row * N + col] = acc[mf][nf][r];
      }
    }
  }
}

// ---------------- causal flash attention, kv-split 2-way ----------------
// Block (pb, ch): 4 waves own consecutive q16s of one q64 range (100% wave
// utilization per tile); chunk ch processes kv tiles [t0, t1) of nt = q_idx+1.
// Partials are UNNORMALIZED (no max tracking -> they just add): o bf16 into
// p0/p1, lsum f32 into lsums[ch][h][q]. Grid 1536, 32KB LDS (double-buffer,
// round-12 lockstep schedule) -> up to 4 blocks/CU (VGPR-capped 16 waves/CU).
__global__ __launch_bounds__(256) void attn_kernel(
    const short* __restrict__ qk, const short* __restrict__ Vt,
    short* __restrict__ p0, short* __restrict__ p1, float* __restrict__ lsums) {
  __shared__ short Ks[2][64 * 64];
  __shared__ short Vs[2][64 * 64];

  const int tid  = threadIdx.x;
  const int lane = tid & 63;
  const int wv   = tid >> 6;
  const int col  = lane & 15;
  const int g    = lane >> 4;

  const int bid   = blockIdx.x;
  const int ch    = bid & 1;
  const int pb    = bid >> 1;
  const int h     = pb % NH;
  const int q_idx = (T_SEQ / 64 - 1) - pb / NH;  // heavy first
  const int q0    = q_idx * 64;
  const int qw    = q0 + wv * 16;
  const int nt    = q_idx + 1;
  const int half  = (nt + 1) >> 1;
  const int t0    = ch ? half : 0;
  const int t1    = ch ? nt : half;
  short* pout     = ch ? p1 : p0;

  const int hq = h * HD;
  const int hk = C_DIM + h * HD;
  const short* Vth = Vt + (size_t)h * HD * T_SEQ;

  const int sidx0 = tid;
  const int sidx1 = 256 + tid;
  const int srow0 = sidx0 >> 3, sslot0 = (sidx0 & 7) ^ (srow0 & 7);
  const int srow1 = sidx1 >> 3, sslot1 = (sidx1 & 7) ^ (srow1 & 7);

#define STAGE(buf, kvoff)                                                               \
  do {                                                                                  \
    __builtin_amdgcn_global_load_lds(                                                   \
        (const __attribute__((address_space(1))) void*)(qk + (size_t)((kvoff) + srow0) * QK_N + hk + sslot0 * 8), \
        (__attribute__((address_space(3))) void*)(&Ks[buf][sidx0 * 8]), 16, 0, 0);      \
    __builtin_amdgcn_global_load_lds(                                                   \
        (const __attribute__((address_space(1))) void*)(qk + (size_t)((kvoff) + srow1) * QK_N + hk + sslot1 * 8), \
        (__attribute__((address_space(3))) void*)(&Ks[buf][sidx1 * 8]), 16, 0, 0);      \
    __builtin_amdgcn_global_load_lds(                                                   \
        (const __attribute__((address_space(1))) void*)(Vth + (size_t)srow0 * T_SEQ + (kvoff) + sslot0 * 8), \
        (__attribute__((address_space(3))) void*)(&Vs[buf][sidx0 * 8]), 16, 0, 0);      \
    __builtin_amdgcn_global_load_lds(                                                   \
        (const __attribute__((address_space(1))) void*)(Vth + (size_t)srow1 * T_SEQ + (kvoff) + sslot1 * 8), \
        (__attribute__((address_space(3))) void*)(&Vs[buf][sidx1 * 8]), 16, 0, 0);      \
  } while (0)

  // Q fragments (pre-scaled): qf[hf] = Q[qw+col][hf*32 + g*8 + j]
  bfx8 qf[2];
#pragma unroll
  for (int hf = 0; hf < 2; hf++)
    qf[hf] = *(const bfx8*)&qk[(size_t)(qw + col) * QK_N + hq + hf * 32 + g * 8];

  // hoisted LDS read offsets (loop-invariant; row&7 == col&7)
  int koff[4][2], voff[2][4];
#pragma unroll
  for (int sub = 0; sub < 4; sub++) {
    int row = sub * 16 + col;
#pragma unroll
    for (int hf = 0; hf < 2; hf++)
      koff[sub][hf] = row * 64 + ((((hf << 2) | g) ^ (row & 7)) * 8);
  }
#pragma unroll
  for (int ks = 0; ks < 2; ks++)
#pragma unroll
    for (int c = 0; c < 4; c++) {
      int row = c * 16 + col;
      voff[ks][c] = row * 64 + ((((ks << 2) | g) ^ (row & 7)) * 8);
    }

  bfx8 ones;
#pragma unroll
  for (int j = 0; j < 8; j++) ones[j] = (short)0x3F80;  // bf16 1.0

  const f32x4 zero = {0.f, 0.f, 0.f, 0.f};
  f32x4 o[4];
#pragma unroll
  for (int c = 0; c < 4; c++) o[c] = zero;
  f32x4 o_l = zero;  // lsum accumulator

  const int qabs = qw + col;

#define TILE_BODY(BUF, KV)                                                              \
  do {                                                                                  \
    if ((KV) <= qw + 15) {                                                              \
      bfx8 kf[4][2];                                                                    \
      _Pragma("unroll") for (int sub = 0; sub < 4; sub++)                               \
          _Pragma("unroll") for (int hf = 0; hf < 2; hf++)                              \
              kf[sub][hf] = *(const bfx8*)&Ks[BUF][koff[sub][hf]];                      \
      bfx8 vtf[2][4];                                                                   \
      _Pragma("unroll") for (int ks = 0; ks < 2; ks++)                                  \
          _Pragma("unroll") for (int c = 0; c < 4; c++)                                 \
              vtf[ks][c] = *(const bfx8*)&Vs[BUF][voff[ks][c]];                         \
      f32x4 s[4];                                                                       \
      __builtin_amdgcn_s_setprio(1);                                                    \
      _Pragma("unroll") for (int sub = 0; sub < 4; sub++) {                             \
        s[sub] = zero;                                                                  \
        s[sub] = MFMA16(kf[sub][0], qf[0], s[sub]);                                     \
        s[sub] = MFMA16(kf[sub][1], qf[1], s[sub]);                                     \
      }                                                                                 \
      __builtin_amdgcn_s_setprio(0);                                                    \
      if (!((KV) + 63 <= qw)) {                                                         \
        _Pragma("unroll") for (int sub = 0; sub < 4; sub++)                             \
            _Pragma("unroll") for (int r = 0; r < 4; r++) {                             \
              int key = (KV) + sub * 16 + 4 * g + r;                                    \
              if (key > qabs) s[sub][r] = -INFINITY;                                    \
            }                                                                           \
      }                                                                                 \
      float p[4][4];                                                                    \
      _Pragma("unroll") for (int sub = 0; sub < 4; sub++)                               \
          _Pragma("unroll") for (int r = 0; r < 4; r++)                                 \
              p[sub][r] = EXP2(s[sub][r]);                                              \
      _Pragma("unroll") for (int ks = 0; ks < 2; ks++) {                                \
        unsigned x0 = packtrunc(p[2 * ks][0], p[2 * ks][1]);                            \
        unsigned y0 = packtrunc(p[2 * ks + 1][0], p[2 * ks + 1][1]);                    \
        unsigned x1 = packtrunc(p[2 * ks][2], p[2 * ks][3]);                            \
        unsigned y1 = packtrunc(p[2 * ks + 1][2], p[2 * ks + 1][3]);                    \
        pl32(x0, y0); pl16(x0, y0);                                                     \
        pl32(x1, y1); pl16(x1, y1);                                                     \
        u32x4 w; w[0] = x0; w[1] = x1; w[2] = y0; w[3] = y1;                            \
        bfx8 pf = __builtin_bit_cast(bfx8, w);                                          \
        __builtin_amdgcn_s_setprio(1);                                                  \
        _Pragma("unroll") for (int c = 0; c < 4; c++)                                   \
            o[c] = MFMA16(vtf[ks][c], pf, o[c]);                                        \
        o_l = MFMA16(ones, pf, o_l);                                                    \
        __builtin_amdgcn_s_setprio(0);                                                  \
      }                                                                                 \
    }                                                                                   \
  } while (0)

  if (t0 < t1) {
    STAGE(0, t0 * 64);
    for (int t = t0; t < t1; t++) {
      const int cur = (t - t0) & 1;
      if (t + 1 < t1) {
        STAGE(cur ^ 1, (t + 1) * 64);
        asm volatile("s_waitcnt vmcnt(4)" ::: "memory");
      } else {
        asm volatile("s_waitcnt vmcnt(0)" ::: "memory");
      }
      __builtin_amdgcn_s_barrier();
      TILE_BODY(cur, t * 64);
      asm volatile("s_waitcnt lgkmcnt(0)" ::: "memory");
      __builtin_amdgcn_s_barrier();
    }
  }

  // write UNNORMALIZED partial O (bf16) + per-q lsum (f32)
  if (g == 0)
    lsums[(size_t)ch * NH * T_SEQ + (size_t)h * T_SEQ + qw + col] = o_l[0];
#pragma unroll
  for (int c = 0; c < 4; c++) {
    bfx4 ov;
#pragma unroll
    for (int r = 0; r < 4; r++) ov[r] = f2bf(o[c][r]);
    *(bfx4*)&pout[(size_t)(qw + col) * C_DIM + h * HD + c * 16 + g * 4] = ov;
  }
#undef TILE_BODY
#undef STAGE
}

// ---------------- combine partials: y = (p0 + p1) / (l0 + l1), in-place into p0 ----------------
__global__ __launch_bounds__(256) void combine_kernel(
    short* __restrict__ p0, const short* __restrict__ p1,
    const float* __restrict__ lsums) {
  int i = blockIdx.x * 256 + threadIdx.x;       // 8-elem groups; 4096*768/8 total
  int base = i * 8;
  int q = base / C_DIM;
  int h = (base % C_DIM) / HD;
  float l = lsums[(size_t)h * T_SEQ + q] +
            lsums[(size_t)NH * T_SEQ + (size_t)h * T_SEQ + q];
  float inv = 1.f / l;
  bfx8 a = *(const bfx8*)&p0[base];
  bfx8 b = *(const bfx8*)&p1[base];
  bfx8 y;
#pragma unroll
  for (int j = 0; j < 8; j++)
    y[j] = f2bf((bf2f(a[j]) + bf2f(b[j])) * inv);
  *(bfx8*)&p0[base] = y;
}

// ---------------- launch ----------------
extern "C" void kernel_launch(void* const* d_in, const int* in_sizes, int n_in,
                              void* d_out, int out_size, void* d_ws, size_t ws_size,
                              hipStream_t stream) {
  const float* x      = (const float*)d_in[0];
  const float* w_attn = (const float*)d_in[1];
  const float* w_proj = (const float*)d_in[2];
  float* out = (float*)d_out;

  char* ws = (char*)d_ws;
  short* xb  = (short*)(ws);                       // 6291456 B (reused as p1 after qkv GEMM)
  short* wab = (short*)(ws + 6291456);             // 3538944 B (tail reused as lsums)
  short* wpb = (short*)(ws + 9830400);             // 1179648 B
  short* qk  = (short*)(ws + 11010048);            // 12582912 B
  short* Vt  = (short*)(ws + 23592960);            // 6291456 B
  short* yb  = (short*)(ws + 29884416);            // 6291456 B  (p0 / combined y)

  short* p1    = xb;                    // dead after gemm_qkv
  float* lsums = (float*)wab;           // dead after gemm_qkv; needs 393216 B

  prep_kernel<<<NB_CONV + NB_TA + NB_TB, 256, 0, stream>>>(x, xb, w_attn, wab, w_proj, wpb);
  gemm_qkv<<<dim3(T_SEQ / 128, QKV_N / 96), 256, 0, stream>>>(xb, wab, qk, Vt, C_DIM);
  attn_kernel<<<(T_SEQ / 64) * NH * 2, 256, 0, stream>>>(qk, Vt, yb, p1, lsums);
  combine_kernel<<<(T_SEQ * C_DIM / 8) / 256, 256, 0, stream>>>(yb, p1, lsums);
  gemm_proj<<<dim3(T_SEQ / 64, C_DIM / 64), 256, 0, stream>>>(yb, wpb, out, C_DIM, C_DIM);
}